// Round 1
// baseline (365.326 us; speedup 1.0000x reference)
//
#include <hip/hip_runtime.h>

// Attention with relative-position embeddings, fused single kernel.
// B=4, H=8, S=512, D=64. fp32 throughout.
// Block = (b, 4-row s-tile), 512 threads (8 waves). Grid = 4*128 = 512.
//
// LDS: Qs[8h][4si][64d] (8 KiB) + Pb[32 rows][544] skewed (68 KiB) = 76 KiB.
// Pb skew: addr = row*544 + t + ((t>>6)<<2)  -> breaks t-stride-64 bank
// collisions for the phase-D per-q vector reads.

#define PBIDX(row, t) (((row) * 544) + (t) + ((((t) >> 6)) << 2))

__global__ __launch_bounds__(512, 2)
void attn_fused(const float* __restrict__ Q, const float* __restrict__ K,
                const float* __restrict__ V, const float* __restrict__ R,
                const int* __restrict__ Mk, float* __restrict__ ans,
                float* __restrict__ pout) {
  extern __shared__ __align__(16) float smem[];
  float* Qs = smem;          // [8][4][64] = 2048 floats
  float* Pb = smem + 2048;   // [32][544]  = 17408 floats

  const int tid = threadIdx.x;
  const int b   = blockIdx.x >> 7;          // 0..3
  const int s0  = (blockIdx.x & 127) << 2;  // 0..508 step 4

  // ---------------- stage Q tile: Qs[h][si][d] ----------------
  {
    const int d4 = tid & 15;          // float4 index within row
    const int si = (tid >> 4) & 3;
    const int h  = tid >> 6;
    const float4 qv = *reinterpret_cast<const float4*>(
        Q + ((((((b << 3) + h) << 9) + (s0 + si)) << 6) + (d4 << 2)));
    *reinterpret_cast<float4*>(Qs + (((h << 2) + si) << 6) + (d4 << 2)) = qv;
  }
  __syncthreads();

  // ---------------- phase B: raw scores -> Pb ----------------
  // thread = (hg in 0..1, tl in 0..31, dgrp in 0..7); d-slice = 8 floats.
  // Register tile: 4 h (hh) x 4 si per thread; K frag reused across si,
  // R frag reused across h. Butterfly-reduce partial dots over dgrp lanes.
  {
    const int dgrp = tid & 7;
    const int tl   = (tid >> 3) & 31;
    const int hg   = tid >> 8;
    const int d0   = dgrp << 3;

    for (int tc = 0; tc < 16; ++tc) {
      const int t = (tc << 5) + tl;

      float kv[4][8];
#pragma unroll
      for (int hh = 0; hh < 4; ++hh) {
        const float* kp =
            K + (((((b << 3) + (hg << 2) + hh) << 9) + t) << 6) + d0;
        const float4 a = *reinterpret_cast<const float4*>(kp);
        const float4 c = *reinterpret_cast<const float4*>(kp + 4);
        kv[hh][0] = a.x; kv[hh][1] = a.y; kv[hh][2] = a.z; kv[hh][3] = a.w;
        kv[hh][4] = c.x; kv[hh][5] = c.y; kv[hh][6] = c.z; kv[hh][7] = c.w;
      }

      float acc[4][4];
#pragma unroll
      for (int hh = 0; hh < 4; ++hh)
#pragma unroll
        for (int si = 0; si < 4; ++si) acc[hh][si] = 0.0f;

#pragma unroll
      for (int si = 0; si < 4; ++si) {
        const float* rp =
            R + (((((b << 9) + s0 + si) << 9) + t) << 6) + d0;
        const float4 a = *reinterpret_cast<const float4*>(rp);
        const float4 c = *reinterpret_cast<const float4*>(rp + 4);
        float rv[8];
        rv[0] = a.x; rv[1] = a.y; rv[2] = a.z; rv[3] = a.w;
        rv[4] = c.x; rv[5] = c.y; rv[6] = c.z; rv[7] = c.w;
#pragma unroll
        for (int hh = 0; hh < 4; ++hh) {
          const float* qp =
              Qs + (((((hg << 2) + hh) << 2) + si) << 6) + d0;
          const float4 qa = *reinterpret_cast<const float4*>(qp);
          const float4 qc = *reinterpret_cast<const float4*>(qp + 4);
          float qv[8];
          qv[0] = qa.x; qv[1] = qa.y; qv[2] = qa.z; qv[3] = qa.w;
          qv[4] = qc.x; qv[5] = qc.y; qv[6] = qc.z; qv[7] = qc.w;
#pragma unroll
          for (int j = 0; j < 8; ++j)
            acc[hh][si] += qv[j] * (kv[hh][j] + rv[j]);
        }
      }

      // reduce partial dots across the 8 dgrp lanes (tid bits 0..2)
#pragma unroll
      for (int hh = 0; hh < 4; ++hh)
#pragma unroll
        for (int si = 0; si < 4; ++si) {
          float v = acc[hh][si];
          v += __shfl_xor(v, 1);
          v += __shfl_xor(v, 2);
          v += __shfl_xor(v, 4);
          acc[hh][si] = v;
        }

      const float bias = (Mk[(b << 9) + t] == 0) ? -1.0e9f : 0.0f;
#pragma unroll
      for (int w = 0; w < 2; ++w) {
        const int idx = (dgrp << 1) + w;  // 0..15
        const int hh = idx >> 2;
        const int si = idx & 3;
        Pb[PBIDX((si << 3) + (hg << 2) + hh, t)] =
            acc[hh][si] * 0.125f + bias;
      }
    }
  }
  __syncthreads();

  // ---------------- phase C: softmax rows + write p_attn ----------------
  {
    const int wv = tid >> 6;
    const int lane = tid & 63;
    for (int rr = 0; rr < 4; ++rr) {
      const int row = (wv << 2) + rr;   // 0..31
      const int si = row >> 3;
      const int h  = row & 7;
      float vv[8];
#pragma unroll
      for (int k = 0; k < 8; ++k)
        vv[k] = Pb[row * 544 + lane + (k << 6) + (k << 2)];

      float m = vv[0];
#pragma unroll
      for (int k = 1; k < 8; ++k) m = fmaxf(m, vv[k]);
      m = fmaxf(m, __shfl_xor(m, 32));
      m = fmaxf(m, __shfl_xor(m, 16));
      m = fmaxf(m, __shfl_xor(m, 8));
      m = fmaxf(m, __shfl_xor(m, 4));
      m = fmaxf(m, __shfl_xor(m, 2));
      m = fmaxf(m, __shfl_xor(m, 1));

      float e[8];
      float ss = 0.0f;
#pragma unroll
      for (int k = 0; k < 8; ++k) {
        e[k] = __expf(vv[k] - m);
        ss += e[k];
      }
      ss += __shfl_xor(ss, 32);
      ss += __shfl_xor(ss, 16);
      ss += __shfl_xor(ss, 8);
      ss += __shfl_xor(ss, 4);
      ss += __shfl_xor(ss, 2);
      ss += __shfl_xor(ss, 1);
      const float inv = 1.0f / ss;

      float* po = pout + ((size_t)((((b << 3) + h) << 9) + s0 + si) << 9);
#pragma unroll
      for (int k = 0; k < 8; ++k) {
        const float p = e[k] * inv;
        Pb[row * 544 + lane + (k << 6) + (k << 2)] = p;
        po[lane + (k << 6)] = p;
      }
    }
  }
  __syncthreads();

  // ---------------- phase D: out = P @ (V + R) ----------------
  // thread = (hgg in 0..3 -> 2 h's, dq in 0..15 -> 4 d's, q in 0..7 -> 64 t's)
  {
    const int q   = tid & 7;
    const int dq  = (tid >> 3) & 15;
    const int hgg = tid >> 7;
    const int d0  = dq << 2;
    const int t0  = q << 6;

    float acc[2][4][4];
#pragma unroll
    for (int hh = 0; hh < 2; ++hh)
#pragma unroll
      for (int si = 0; si < 4; ++si)
#pragma unroll
        for (int c = 0; c < 4; ++c) acc[hh][si][c] = 0.0f;

    for (int tt = 0; tt < 64; tt += 4) {
      float pc[2][4][4];
#pragma unroll
      for (int hh = 0; hh < 2; ++hh)
#pragma unroll
        for (int si = 0; si < 4; ++si) {
          const float4 p4 = *reinterpret_cast<const float4*>(
              Pb + PBIDX((si << 3) + (hgg << 1) + hh, t0 + tt));
          pc[hh][si][0] = p4.x; pc[hh][si][1] = p4.y;
          pc[hh][si][2] = p4.z; pc[hh][si][3] = p4.w;
        }
#pragma unroll
      for (int u = 0; u < 4; ++u) {
        const int t = t0 + tt + u;
        float4 v4[2];
#pragma unroll
        for (int hh = 0; hh < 2; ++hh)
          v4[hh] = *reinterpret_cast<const float4*>(
              V + (((((b << 3) + (hgg << 1) + hh) << 9) + t) << 6) + d0);
#pragma unroll
        for (int si = 0; si < 4; ++si) {
          const float4 r4 = *reinterpret_cast<const float4*>(
              R + (((((b << 9) + s0 + si) << 9) + t) << 6) + d0);
#pragma unroll
          for (int hh = 0; hh < 2; ++hh) {
            const float p = pc[hh][si][u];
            acc[hh][si][0] += p * (v4[hh].x + r4.x);
            acc[hh][si][1] += p * (v4[hh].y + r4.y);
            acc[hh][si][2] += p * (v4[hh].z + r4.z);
            acc[hh][si][3] += p * (v4[hh].w + r4.w);
          }
        }
      }
    }

    // reduce across the 8 q-lanes (tid bits 0..2)
#pragma unroll
    for (int hh = 0; hh < 2; ++hh)
#pragma unroll
      for (int si = 0; si < 4; ++si)
#pragma unroll
        for (int c = 0; c < 4; ++c) {
          float v = acc[hh][si][c];
          v += __shfl_xor(v, 1);
          v += __shfl_xor(v, 2);
          v += __shfl_xor(v, 4);
          acc[hh][si][c] = v;
        }

    // lane q writes (hh = q>>2, si = q&3), 4 d's
    const int hh = q >> 2;
    const int si = q & 3;
    float4 o;
    o.x = acc[hh][si][0];
    o.y = acc[hh][si][1];
    o.z = acc[hh][si][2];
    o.w = acc[hh][si][3];
    *reinterpret_cast<float4*>(
        ans + (((((b << 3) + (hgg << 1) + hh) << 9) + s0 + si) << 6) + d0) = o;
  }
}

extern "C" void kernel_launch(void* const* d_in, const int* in_sizes, int n_in,
                              void* d_out, int out_size, void* d_ws, size_t ws_size,
                              hipStream_t stream) {
  const float* Q  = (const float*)d_in[0];
  const float* K  = (const float*)d_in[1];
  const float* V  = (const float*)d_in[2];
  const float* R  = (const float*)d_in[3];
  const int*   Mk = (const int*)d_in[4];
  float* ans  = (float*)d_out;
  float* pout = ans + (size_t)4 * 8 * 512 * 64;  // p_attn after ans

  const size_t smem_bytes = (2048 + 32 * 544) * sizeof(float);  // 77,824 B
  hipLaunchKernelGGL(attn_fused, dim3(512), dim3(512), smem_bytes, stream,
                     Q, K, V, R, Mk, ans, pout);
}

// Round 2
// 198.438 us; speedup vs baseline: 1.8410x; 1.8410x over previous
//
#include <hip/hip_runtime.h>

// Fused rel-pos attention. B=4, H=8, S=512, D=64, fp32 in/out.
// Block = (b, 2-row s-tile), 256 threads (4 waves). Grid = 4*256 = 1024
// -> exactly 4 blocks/CU, 16 waves/CU.
// LDS: Qs[2][8][64] fp32 (4 KB) + Pb[16][520] bf16 (16.25 KB) = 20.7 KB.

__device__ __forceinline__ unsigned short f2bf(float x) {
  unsigned int u = __float_as_uint(x);
  u += 0x7fffu + ((u >> 16) & 1u);   // round-to-nearest-even
  return (unsigned short)(u >> 16);
}
__device__ __forceinline__ float bf2f(unsigned short s) {
  return __uint_as_float(((unsigned int)s) << 16);
}

__global__ __launch_bounds__(256, 4)
void attn_v2(const float* __restrict__ Q, const float* __restrict__ K,
             const float* __restrict__ V, const float* __restrict__ R,
             const int* __restrict__ Mk, float* __restrict__ ans,
             float* __restrict__ pout) {
  __shared__ __align__(16) float Qs[2][8][64];
  __shared__ unsigned short Pb[16][520];

  const int tid = threadIdx.x;
  const int b  = blockIdx.x >> 8;
  const int s0 = (blockIdx.x & 255) << 1;

  // ---------------- Phase A: stage Q tile ----------------
  {
    const int d4 = tid & 15;
    const int h  = (tid >> 4) & 7;
    const int si = tid >> 7;
    *reinterpret_cast<float4*>(&Qs[si][h][d4 << 2]) =
        *reinterpret_cast<const float4*>(
            Q + ((size_t)((((b << 3) + h) << 9) + s0 + si) << 6) + (d4 << 2));
  }
  __syncthreads();

  // ---------------- Phase B: scores -> Pb (bf16, scaled, unmasked) --------
  // lanes: dgrp = tid&7 owns d-slice of 8; tl = tid>>3 owns t row.
  {
    const int dgrp = tid & 7;
    const int tl   = tid >> 3;      // 0..31
    const int d0   = dgrp << 3;
    const bool b0 = (dgrp & 1) != 0, b1 = (dgrp & 2) != 0, b2 = (dgrp & 4) != 0;

#pragma unroll
    for (int hg = 0; hg < 2; ++hg) {
      // hoist Q fragments for 4 heads x 2 s-rows
      float q[2][4][8];
#pragma unroll
      for (int si = 0; si < 2; ++si)
#pragma unroll
        for (int hh = 0; hh < 4; ++hh) {
          const float4 a = *reinterpret_cast<const float4*>(&Qs[si][(hg << 2) + hh][d0]);
          const float4 c = *reinterpret_cast<const float4*>(&Qs[si][(hg << 2) + hh][d0 + 4]);
          q[si][hh][0] = a.x; q[si][hh][1] = a.y; q[si][hh][2] = a.z; q[si][hh][3] = a.w;
          q[si][hh][4] = c.x; q[si][hh][5] = c.y; q[si][hh][6] = c.z; q[si][hh][7] = c.w;
        }

      for (int tc = 0; tc < 16; ++tc) {
        const int t = (tc << 5) + tl;

        float rv[2][8];
#pragma unroll
        for (int si = 0; si < 2; ++si) {
          const float* rp =
              R + ((size_t)((((b << 9) + s0 + si) << 9) + t) << 6) + d0;
          const float4 a = *reinterpret_cast<const float4*>(rp);
          const float4 c = *reinterpret_cast<const float4*>(rp + 4);
          rv[si][0] = a.x; rv[si][1] = a.y; rv[si][2] = a.z; rv[si][3] = a.w;
          rv[si][4] = c.x; rv[si][5] = c.y; rv[si][6] = c.z; rv[si][7] = c.w;
        }

        float acc[2][4];
#pragma unroll
        for (int hp = 0; hp < 2; ++hp) {   // 2 heads at a time (reg pressure)
          float kv[2][8];
#pragma unroll
          for (int j = 0; j < 2; ++j) {
            const float* kp =
                K + ((size_t)((((b << 3) + (hg << 2) + (hp << 1) + j) << 9) + t) << 6) + d0;
            const float4 a = *reinterpret_cast<const float4*>(kp);
            const float4 c = *reinterpret_cast<const float4*>(kp + 4);
            kv[j][0] = a.x; kv[j][1] = a.y; kv[j][2] = a.z; kv[j][3] = a.w;
            kv[j][4] = c.x; kv[j][5] = c.y; kv[j][6] = c.z; kv[j][7] = c.w;
          }
#pragma unroll
          for (int si = 0; si < 2; ++si)
#pragma unroll
            for (int j = 0; j < 2; ++j) {
              float s = 0.0f;
#pragma unroll
              for (int d = 0; d < 8; ++d)
                s += q[si][(hp << 1) + j][d] * (kv[j][d] + rv[si][d]);
              acc[si][(hp << 1) + j] = s;
            }
        }

        // Distributing tree-reduce over the 8 dgrp lanes.
        // value idx = si*4+hh; lane dgrp ends with the full sum of combo dgrp.
        float n0 = (b0 ? acc[0][1] : acc[0][0]) + __shfl_xor(b0 ? acc[0][0] : acc[0][1], 1);
        float n1 = (b0 ? acc[0][3] : acc[0][2]) + __shfl_xor(b0 ? acc[0][2] : acc[0][3], 1);
        float n2 = (b0 ? acc[1][1] : acc[1][0]) + __shfl_xor(b0 ? acc[1][0] : acc[1][1], 1);
        float n3 = (b0 ? acc[1][3] : acc[1][2]) + __shfl_xor(b0 ? acc[1][2] : acc[1][3], 1);
        float m0 = (b1 ? n1 : n0) + __shfl_xor(b1 ? n0 : n1, 2);
        float m1 = (b1 ? n3 : n2) + __shfl_xor(b1 ? n2 : n3, 2);
        float f  = (b2 ? m1 : m0) + __shfl_xor(b2 ? m0 : m1, 4);

        const int row = ((dgrp >> 2) << 3) + (hg << 2) + (dgrp & 3);
        Pb[row][t] = f2bf(f * 0.125f);
      }
    }
  }
  __syncthreads();

  // ---------------- Phase C: softmax + write p_attn ----------------
  {
    const int w = tid >> 6;
    const int lane = tid & 63;
    float bias[8];
#pragma unroll
    for (int k = 0; k < 8; ++k)
      bias[k] = Mk[(b << 9) + lane + (k << 6)] ? 0.0f : -1.0e9f;

    for (int rr = 0; rr < 4; ++rr) {
      const int row = (w << 2) + rr;   // 0..15
      const int si = row >> 3;
      const int h  = row & 7;

      float v[8];
#pragma unroll
      for (int k = 0; k < 8; ++k)
        v[k] = bf2f(Pb[row][lane + (k << 6)]) + bias[k];

      float m = v[0];
#pragma unroll
      for (int k = 1; k < 8; ++k) m = fmaxf(m, v[k]);
      m = fmaxf(m, __shfl_xor(m, 1));
      m = fmaxf(m, __shfl_xor(m, 2));
      m = fmaxf(m, __shfl_xor(m, 4));
      m = fmaxf(m, __shfl_xor(m, 8));
      m = fmaxf(m, __shfl_xor(m, 16));
      m = fmaxf(m, __shfl_xor(m, 32));

      float e[8];
      float ss = 0.0f;
#pragma unroll
      for (int k = 0; k < 8; ++k) {
        e[k] = __expf(v[k] - m);
        ss += e[k];
      }
      ss += __shfl_xor(ss, 1);
      ss += __shfl_xor(ss, 2);
      ss += __shfl_xor(ss, 4);
      ss += __shfl_xor(ss, 8);
      ss += __shfl_xor(ss, 16);
      ss += __shfl_xor(ss, 32);
      const float inv = 1.0f / ss;

      float* po = pout + ((size_t)((((b << 3) + h) << 9) + s0 + si) << 9);
#pragma unroll
      for (int k = 0; k < 8; ++k) {
        const float p = e[k] * inv;
        po[lane + (k << 6)] = p;
        Pb[row][lane + (k << 6)] = f2bf(p);
      }
    }
  }
  __syncthreads();

  // ---------------- Phase D: out = P @ (V + R) ----------------
  // wave hw owns 2 heads, all t; lanes (tg 0..3, d4 0..15).
  {
    const int hw = tid >> 6;
    const int tg = (tid >> 4) & 3;
    const int d4 = tid & 15;
    const int dd = d4 << 2;

    float acc[2][2][4];
#pragma unroll
    for (int si = 0; si < 2; ++si)
#pragma unroll
      for (int hh = 0; hh < 2; ++hh)
#pragma unroll
        for (int c = 0; c < 4; ++c) acc[si][hh][c] = 0.0f;

#pragma unroll 2
    for (int i = 0; i < 128; ++i) {
      const int t = (i << 2) + tg;
      float4 r4[2], v4[2];
#pragma unroll
      for (int si = 0; si < 2; ++si)
        r4[si] = *reinterpret_cast<const float4*>(
            R + ((size_t)((((b << 9) + s0 + si) << 9) + t) << 6) + dd);
#pragma unroll
      for (int hh = 0; hh < 2; ++hh)
        v4[hh] = *reinterpret_cast<const float4*>(
            V + ((size_t)((((b << 3) + (hw << 1) + hh) << 9) + t) << 6) + dd);

      float p[2][2];
#pragma unroll
      for (int si = 0; si < 2; ++si)
#pragma unroll
        for (int hh = 0; hh < 2; ++hh)
          p[si][hh] = bf2f(Pb[(si << 3) + (hw << 1) + hh][t]);

#pragma unroll
      for (int si = 0; si < 2; ++si)
#pragma unroll
        for (int hh = 0; hh < 2; ++hh) {
          acc[si][hh][0] += p[si][hh] * (v4[hh].x + r4[si].x);
          acc[si][hh][1] += p[si][hh] * (v4[hh].y + r4[si].y);
          acc[si][hh][2] += p[si][hh] * (v4[hh].z + r4[si].z);
          acc[si][hh][3] += p[si][hh] * (v4[hh].w + r4[si].w);
        }
    }

#pragma unroll
    for (int si = 0; si < 2; ++si)
#pragma unroll
      for (int hh = 0; hh < 2; ++hh)
#pragma unroll
        for (int c = 0; c < 4; ++c) {
          float x = acc[si][hh][c];
          x += __shfl_xor(x, 16);
          x += __shfl_xor(x, 32);
          acc[si][hh][c] = x;
        }

    if (tg == 0) {
#pragma unroll
      for (int si = 0; si < 2; ++si)
#pragma unroll
        for (int hh = 0; hh < 2; ++hh) {
          float4 o;
          o.x = acc[si][hh][0]; o.y = acc[si][hh][1];
          o.z = acc[si][hh][2]; o.w = acc[si][hh][3];
          *reinterpret_cast<float4*>(
              ans + ((size_t)((((b << 3) + (hw << 1) + hh) << 9) + s0 + si) << 6) + dd) = o;
        }
    }
  }
}

extern "C" void kernel_launch(void* const* d_in, const int* in_sizes, int n_in,
                              void* d_out, int out_size, void* d_ws, size_t ws_size,
                              hipStream_t stream) {
  const float* Q  = (const float*)d_in[0];
  const float* K  = (const float*)d_in[1];
  const float* V  = (const float*)d_in[2];
  const float* R  = (const float*)d_in[3];
  const int*   Mk = (const int*)d_in[4];
  float* ans  = (float*)d_out;
  float* pout = ans + (size_t)4 * 8 * 512 * 64;  // p_attn after ans

  hipLaunchKernelGGL(attn_v2, dim3(1024), dim3(256), 0, stream,
                     Q, K, V, R, Mk, ans, pout);
}